// Round 20
// baseline (258.579 us; speedup 1.0000x reference)
//
#include <hip/hip_runtime.h>
#include <math.h>

#define S_LEN 2048
#define DIM   1024
#define HEADS 16
#define DK    64
#define BATCH 4

typedef __bf16 bf16;
typedef bf16  bf16x8 __attribute__((ext_vector_type(8)));
typedef bf16  bf16x4 __attribute__((ext_vector_type(4)));
typedef float f32x4  __attribute__((ext_vector_type(4)));
typedef unsigned long long u64;

#define QSCALE (0.125f * 1.44269504088896f)   // 1/sqrt(dk) * log2(e)

__device__ __forceinline__ void gload16(const void* g, void* l) {
  __builtin_amdgcn_global_load_lds((const __attribute__((address_space(1))) void*)g,
                                   (__attribute__((address_space(3))) void*)l, 16, 0, 0);
}
__device__ __forceinline__ float exp2fast(float x) {
  float r; asm("v_exp_f32 %0, %1" : "=v"(r) : "v"(x)); return r;
}
__device__ __forceinline__ unsigned cvt_pk_bf16(float a, float b) {
  unsigned r; asm("v_cvt_pk_bf16_f32 %0, %1, %2" : "=v"(r) : "v"(a), "v"(b)); return r;
}

// ---------------------------------------------------------------------------
// BW pass: f32->bf16 conversion of q/k/v + weights (mask pack moved into
// gemm_qkv tail blocks).
// ---------------------------------------------------------------------------
__global__ __launch_bounds__(256)
void conv_pack(const float* __restrict__ q, const float* __restrict__ k,
               const float* __restrict__ v,
               const float* __restrict__ Wq, const float* __restrict__ Wk,
               const float* __restrict__ Wv, const float* __restrict__ Wo,
               bf16* __restrict__ qB, bf16* __restrict__ kB, bf16* __restrict__ vB,
               bf16* __restrict__ WqB, bf16* __restrict__ WkB,
               bf16* __restrict__ WvB, bf16* __restrict__ WoB)
{
  const int y = blockIdx.y;
  const float* in;
  bf16* out;
  size_t idx;
  if (y < 3) {
    in  = (y == 0) ? q  : (y == 1) ? k  : v;
    out = (y == 0) ? qB : (y == 1) ? kB : vB;
    idx = ((size_t)blockIdx.x * 256 + threadIdx.x) * 8;
  } else {
    if (blockIdx.x >= 2048) return;
    const int wsel = blockIdx.x >> 9, inner = blockIdx.x & 511;
    in  = (wsel == 0) ? Wq  : (wsel == 1) ? Wk  : (wsel == 2) ? Wv  : Wo;
    out = (wsel == 0) ? WqB : (wsel == 1) ? WkB : (wsel == 2) ? WvB : WoB;
    idx = ((size_t)inner * 256 + threadIdx.x) * 8;
  }
  float4 a = *reinterpret_cast<const float4*>(&in[idx]);
  float4 b = *reinterpret_cast<const float4*>(&in[idx + 4]);
  bf16x8 r;
  r[0] = (bf16)a.x; r[1] = (bf16)a.y; r[2] = (bf16)a.z; r[3] = (bf16)a.w;
  r[4] = (bf16)b.x; r[5] = (bf16)b.y; r[6] = (bf16)b.z; r[7] = (bf16)b.w;
  *reinterpret_cast<bf16x8*>(&out[idx]) = r;
}

// ---------------------------------------------------------------------------
// GEMM v2 plumbing (round-19 structure): BM=256, BN=128, BK=32, 4x8 frag,
// 3 LDS buffers, depth-2 counted vmcnt.
// ---------------------------------------------------------------------------
#define G2_SETUP()                                                             \
  const int lane = tid & 63;                                                   \
  const int l15  = lane & 15, lg = lane >> 4;                                  \
  const int w    = tid >> 6;                                                   \
  const char* srcA0; const char* srcA1; const char* srcA2; const char* srcA3;  \
  const char* srcB0; const char* srcB1;                                        \
  char* dA0; char* dA1; char* dA2; char* dA3; char* dB0; char* dB1;            \
  {                                                                            \
    char* base = (char*)&AB[0];                                                \
    _Pragma("unroll")                                                          \
    for (int j = 0; j < 4; ++j) {                                              \
      const int c = j * 256 + tid;                                             \
      const int r = c >> 2;                                                    \
      const int cG = ((c & 3) << 4) ^ (((r >> 1) & 3) << 4);                   \
      const char* s = (const char*)A + (size_t)(m0 + r) * 2048 + cG;           \
      char* d = base + c * 16;                                                 \
      if (j == 0) { srcA0 = s; dA0 = d; } else if (j == 1) { srcA1 = s; dA1 = d; } \
      else if (j == 2) { srcA2 = s; dA2 = d; } else { srcA3 = s; dA3 = d; }    \
    }                                                                          \
    _Pragma("unroll")                                                          \
    for (int j = 0; j < 2; ++j) {                                              \
      const int c = j * 256 + tid;                                             \
      const int r = c >> 2;                                                    \
      const int cG = ((c & 3) << 4) ^ (((r >> 1) & 3) << 4);                   \
      const char* s = (const char*)W + (size_t)(n0 + r) * 2048 + cG;           \
      char* d = base + 16384 + c * 16;                                         \
      if (j == 0) { srcB0 = s; dB0 = d; } else { srcB1 = s; dB1 = d; }         \
    }                                                                          \
  }

#define G2_STAGE(SB) do {                                                      \
    gload16(srcA0, dA0 + (SB)); gload16(srcA1, dA1 + (SB));                    \
    gload16(srcA2, dA2 + (SB)); gload16(srcA3, dA3 + (SB));                    \
    gload16(srcB0, dB0 + (SB)); gload16(srcB1, dB1 + (SB));                    \
    srcA0 += 64; srcA1 += 64; srcA2 += 64; srcA3 += 64;                        \
    srcB0 += 64; srcB1 += 64;                                                  \
  } while (0)

#define G2_MAINLOOP()                                                          \
  G2_STAGE(0);                                                                 \
  G2_STAGE(24576);                                                             \
  const unsigned aswz = ((l15 >> 1) & 3) << 4;                                 \
  const unsigned aoff = (unsigned)(w * 64 + l15) * 64 + ((lg * 16) ^ aswz);    \
  const unsigned boff = 16384u + (unsigned)l15 * 64 + ((lg * 16) ^ aswz);      \
  const char* ABB = (const char*)&AB[0];                                       \
  unsigned tb = 0, sb = 2u * 24576;                                            \
  f32x4 acc[4][8] = {};                                                        \
  for (int t = 0; t < 32; ++t) {                                               \
    if (t < 30) {                                                              \
      G2_STAGE(sb);                                                            \
      asm volatile("s_waitcnt vmcnt(12)" ::: "memory");                        \
    } else if (t == 30) {                                                      \
      asm volatile("s_waitcnt vmcnt(6)" ::: "memory");                         \
    } else {                                                                   \
      asm volatile("s_waitcnt vmcnt(0)" ::: "memory");                         \
    }                                                                          \
    __builtin_amdgcn_s_barrier();                                              \
    asm volatile("" ::: "memory");                                             \
    bf16x8 af[4], bfr[8];                                                      \
    _Pragma("unroll")                                                          \
    for (int i = 0; i < 4; ++i)                                                \
      af[i]  = *reinterpret_cast<const bf16x8*>(ABB + tb + aoff + i * 1024);   \
    _Pragma("unroll")                                                          \
    for (int i = 0; i < 8; ++i)                                                \
      bfr[i] = *reinterpret_cast<const bf16x8*>(ABB + tb + boff + i * 1024);   \
    __builtin_amdgcn_s_setprio(1);                                             \
    _Pragma("unroll")                                                          \
    for (int mi = 0; mi < 4; ++mi)                                             \
      _Pragma("unroll")                                                        \
      for (int ni = 0; ni < 8; ++ni)                                           \
        acc[mi][ni] = __builtin_amdgcn_mfma_f32_16x16x32_bf16(af[mi], bfr[ni], acc[mi][ni], 0, 0, 0); \
    __builtin_amdgcn_s_setprio(0);                                             \
    asm volatile("" ::: "memory");                                             \
    __builtin_amdgcn_s_barrier();                                              \
    asm volatile("" ::: "memory");                                             \
    tb = (tb == 2u * 24576) ? 0u : tb + 24576;                                 \
    sb = (sb == 2u * 24576) ? 0u : sb + 24576;                                 \
  }

// Merged QKV (blocks 0..767) + mask bitpack tail (blocks 768..4863, short
// streaming blocks that fill the GEMM's drain tail -- NOT round-13's long
// straggler fusion).
__global__ __launch_bounds__(256, 2)
void gemm_qkv(const bf16* __restrict__ qB, const bf16* __restrict__ kB,
              const bf16* __restrict__ vB,
              const bf16* __restrict__ WqB, const bf16* __restrict__ WkB,
              const bf16* __restrict__ WvB,
              const float* __restrict__ bq, const float* __restrict__ bk,
              const float* __restrict__ bv,
              bf16* __restrict__ Qb, bf16* __restrict__ Kb,
              bf16* __restrict__ Vt,
              const int* __restrict__ mask, u64* __restrict__ bits)
{
  __shared__ __align__(16) char AB[3 * 24576];   // 72 KB
  const int tid = threadIdx.x;

  if (blockIdx.x >= 768) {
    // ---- mask bitpack: 4096 blocks x 64 u64 words (16 ballots/wave) ----
    const int p = blockIdx.x - 768;
    const int lane = tid & 63;
    const size_t w0 = (size_t)p * 64 + (tid >> 6);
    #pragma unroll
    for (int it = 0; it < 16; ++it) {
      const size_t ww = w0 + it * 4;
      const u64 bb = __ballot(mask[ww * 64 + lane] != 0);
      if (lane == 0) bits[ww] = bb;
    }
    return;
  }

  const int which = blockIdx.x >> 8;
  const int inner = blockIdx.x & 255;
  const bf16* A     = (which == 0) ? qB  : (which == 1) ? kB  : vB;
  const bf16* W     = (which == 0) ? WqB : (which == 1) ? WkB : WvB;
  const float* bias = (which == 0) ? bq  : (which == 1) ? bk  : bv;

  const int L  = (inner & 7) * 32 + (inner >> 3);   // XCD-chunked
  const int m0 = (L >> 3) * 256, n0 = (L & 7) * 128;

  G2_SETUP();
  G2_MAINLOOP();

  #pragma unroll
  for (int ni = 0; ni < 8; ++ni) {
    const int col = n0 + ni * 16 + l15;
    const float bi = bias[col];
    #pragma unroll
    for (int mi = 0; mi < 4; ++mi) {
      const int row0 = m0 + w * 64 + mi * 16 + lg * 4;
      if (which == 0) {
        #pragma unroll
        for (int r = 0; r < 4; ++r)
          Qb[(size_t)(row0 + r) * DIM + col] = (bf16)((acc[mi][ni][r] + bi) * QSCALE);
      } else if (which == 1) {
        #pragma unroll
        for (int r = 0; r < 4; ++r)
          Kb[(size_t)(row0 + r) * DIM + col] = (bf16)(acc[mi][ni][r] + bi);
      } else {
        bf16x4 vv;
        #pragma unroll
        for (int r = 0; r < 4; ++r) vv[r] = (bf16)(acc[mi][ni][r] + bi);
        const int seq = row0 & (S_LEN - 1);
        const int t6  = seq & 63;
        const int p0  = (seq & ~63) + ((t6 >> 5) << 5) + (((t6 >> 2) & 3) << 3)
                      + (((t6 >> 4) & 1) << 2);
        *reinterpret_cast<bf16x4*>(
            &Vt[((size_t)(row0 >> 11) * DIM + col) * S_LEN + p0]) = vv;
      }
    }
  }
}

// O-projection (unchanged round-19 structure).
__global__ __launch_bounds__(256, 2)
void gemm_out(const bf16* __restrict__ A, const bf16* __restrict__ W,
              const float* __restrict__ bias, float* __restrict__ out)
{
  __shared__ __align__(16) char AB[3 * 24576];
  const int tid = threadIdx.x;
  const int L  = (blockIdx.x & 7) * 32 + (blockIdx.x >> 3);
  const int m0 = (L >> 3) * 256, n0 = (L & 7) * 128;

  G2_SETUP();
  G2_MAINLOOP();

  #pragma unroll
  for (int ni = 0; ni < 8; ++ni) {
    const int col = n0 + ni * 16 + l15;
    const float bi = bias[col];
    #pragma unroll
    for (int mi = 0; mi < 4; ++mi) {
      const int row0 = m0 + w * 64 + mi * 16 + lg * 4;
      #pragma unroll
      for (int r = 0; r < 4; ++r)
        out[(size_t)(row0 + r) * DIM + col] = acc[mi][ni][r] + bi;
    }
  }
}

// ---------------------------------------------------------------------------
// Flash attention: KVBLK=128 staging (K 2x16KB + V 2x16KB LDS), computed as
// two 64-kv halves per staged tile -> HALF the barrier/drain events of
// round 16, same VGPR (sc/W reused per half). V rows are 256B: XOR swizzle
// (l15&7)<<5 (2-way alias = free); all read offsets lane-constant.
// ---------------------------------------------------------------------------
__global__ __launch_bounds__(512, 2)
void attn_fwd(const bf16* __restrict__ Qb, const bf16* __restrict__ Kb,
              const bf16* __restrict__ Vt, const u64* __restrict__ mbits,
              bf16* __restrict__ ctx)
{
  __shared__ __align__(16) bf16 Kbuf[2][128][64];   // 2 x 16 KB, rows 128 B
  __shared__ __align__(16) bf16 Vbuf[2][64][128];   // 2 x 16 KB, rows 256 B
  __shared__ u64 lutm[16];

  const int tid  = threadIdx.x;
  const int lane = tid & 63;
  const int l15  = lane & 15, lg = lane >> 4;
  const int L  = (blockIdx.x & 7) * 64 + (blockIdx.x >> 3);
  const int qi = L & 7;
  const int hb = L >> 3;
  const int h  = hb & 15, b = hb >> 4;
  const int w  = tid >> 6;
  const int qbase = qi * 256 + w * 32;

  if (tid < 16) {
    lutm[tid] = ((tid & 1) ? 0xFFFFull : 0) | ((tid & 2) ? 0xFFFF0000ull : 0)
              | ((tid & 4) ? 0xFFFF00000000ull : 0)
              | ((tid & 8) ? 0xFFFF000000000000ull : 0);
  }

  // --- staging addresses: K = 128 rows x 128 B (2 chunks/thread),
  //     V = 64 rows x 256 B (2 chunks/thread)
  const int krr = tid >> 3;                       // 0..63 (second chunk +64)
  const int kcG = ((tid & 7) << 4) ^ ((krr & 7) << 4);
  const char* gk0 = (const char*)Kb + ((size_t)(b * S_LEN + krr) * DIM + h * DK) * 2 + kcG;
  const char* gk1 = (const char*)Kb + ((size_t)(b * S_LEN + krr + 64) * DIM + h * DK) * 2 + kcG;
  const int vrr = tid >> 4;                       // 0..31 (second chunk +32)
  const unsigned vcG = (unsigned)(((tid & 15) << 4) ^ ((vrr & 7) << 5));
  const char* gv0 = (const char*)Vt + ((size_t)b * DIM + h * DK + vrr) * (S_LEN * 2) + vcG;
  const char* gv1 = (const char*)Vt + ((size_t)b * DIM + h * DK + vrr + 32) * (S_LEN * 2) + vcG;
  char* lK0 = (char*)&Kbuf[0][0][0] + tid * 16;
  char* lV0 = (char*)&Vbuf[0][0][0] + tid * 16;

  // --- hoisted read offsets
  const unsigned xo  = (l15 & 7) << 4;
  const unsigned ko0 = l15 * 128 + ((lg * 16) ^ xo);
  const unsigned ko1 = l15 * 128 + (((64 + lg * 16)) ^ xo);
  const unsigned vo0 = l15 * 256 + ((lg * 16) ^ ((l15 & 3) << 5));
  const unsigned vo1 = l15 * 256 + (((64 + lg * 16)) ^ ((l15 & 3) << 5));
  const unsigned vhx = (l15 & 4) << 5;            // bit-7 part of V swizzle
  const char* KB = (const char*)&Kbuf[0][0][0];
  const char* VB = (const char*)&Vbuf[0][0][0];

  bf16x8 qf[2][2];
  #pragma unroll
  for (int qg = 0; qg < 2; ++qg) {
    const size_t qrow = (size_t)b * S_LEN + qbase + qg * 16 + l15;
    #pragma unroll
    for (int s = 0; s < 2; ++s)
      qf[qg][s] = *reinterpret_cast<const bf16x8*>(&Qb[qrow * DIM + h * DK + s * 32 + lg * 8]);
  }

  bf16x8 onesf;
  #pragma unroll
  for (int j = 0; j < 8; ++j) onesf[j] = (bf16)1.0f;

  union pqu { unsigned u[8]; bf16x8 frag[2]; };

  f32x4 o[2][4] = {};
  f32x4 o_l[2] = {};
  const u64* mp0 = mbits + ((size_t)b * S_LEN + qbase + l15) * (S_LEN / 64);
  const u64* mp1 = mp0 + (size_t)16 * (S_LEN / 64);

  // prologue: stage tile 0 (128 kv), load mask words 0,1
  gload16(gk0, lK0); gload16(gk1, lK0 + 8192);
  gload16(gv0, lV0); gload16(gv1, lV0 + 8192);
  gk0 += 128 * DIM * 2; gk1 += 128 * DIM * 2;
  gv0 += 256;           gv1 += 256;
  u64 mbc[2][2] = { { mp0[0], mp0[1] }, { mp1[0], mp1[1] } };
  mp0 += 2; mp1 += 2;

  const int NT = S_LEN / 128;   // 16
  for (int t = 0; t < NT; ++t) {
    asm volatile("s_waitcnt vmcnt(0)" ::: "memory");
    __syncthreads();

    u64 mbn[2][2] = {{0,0},{0,0}};
    if (t + 1 < NT) {
      mbn[0][0] = mp0[0]; mbn[0][1] = mp0[1];
      mbn[1][0] = mp1[0]; mbn[1][1] = mp1[1];
      mp0 += 2; mp1 += 2;
      const unsigned nb = ((t + 1) & 1) << 14;
      gload16(gk0, lK0 + nb); gload16(gk1, lK0 + nb + 8192);
      gload16(gv0, lV0 + nb); gload16(gv1, lV0 + nb + 8192);
      gk0 += 128 * DIM * 2; gk1 += 128 * DIM * 2;
      gv0 += 256;           gv1 += 256;
    }

    const unsigned tb = (t & 1) << 14;

    #pragma unroll
    for (int half = 0; half < 2; ++half) {
      const unsigned kbase = tb + half * 8192;
      const unsigned vbase = tb + (((unsigned)(half << 7)) ^ vhx);

      // --- QK^T (this half)
      f32x4 sc[2][4] = {};
      __builtin_amdgcn_s_setprio(1);
      #pragma unroll
      for (int s = 0; s < 2; ++s) {
        const char* kp = KB + kbase + (s ? ko1 : ko0);
        #pragma unroll
        for (int nf = 0; nf < 4; ++nf) {
          bf16x8 kf = *reinterpret_cast<const bf16x8*>(kp + nf * 2048);
          sc[0][nf] = __builtin_amdgcn_mfma_f32_16x16x32_bf16(kf, qf[0][s], sc[0][nf], 0, 0, 0);
          sc[1][nf] = __builtin_amdgcn_mfma_f32_16x16x32_bf16(kf, qf[1][s], sc[1][nf], 0, 0, 0);
        }
      }
      __builtin_amdgcn_s_setprio(0);

      // --- softmax + pack (mask via LDS LUT)
      pqu W[2];
      #pragma unroll
      for (int qg = 0; qg < 2; ++qg) {
        const u64 sh = mbc[qg][half] >> (lg * 4);
        #pragma unroll
        for (int nf = 0; nf < 4; ++nf) {
          const unsigned idx = ((unsigned)(sh >> (nf * 16))) & 15u;
          const u64 mk = lutm[idx];
          float e0 = exp2fast(sc[qg][nf][0]);
          float e1 = exp2fast(sc[qg][nf][1]);
          float e2 = exp2fast(sc[qg][nf][2]);
          float e3 = exp2fast(sc[qg][nf][3]);
          W[qg].u[nf * 2 + 0] = cvt_pk_bf16(e0, e1) & (unsigned)mk;
          W[qg].u[nf * 2 + 1] = cvt_pk_bf16(e2, e3) & (unsigned)(mk >> 32);
        }
      }

      // --- PV (this half)
      __builtin_amdgcn_s_setprio(1);
      #pragma unroll
      for (int s = 0; s < 2; ++s) {
        const char* vp = VB + vbase + (s ? vo1 : vo0);
        #pragma unroll
        for (int nf = 0; nf < 4; ++nf) {
          bf16x8 vf = *reinterpret_cast<const bf16x8*>(vp + nf * 4096);
          o[0][nf] = __builtin_amdgcn_mfma_f32_16x16x32_bf16(W[0].frag[s], vf, o[0][nf], 0, 0, 0);
          o[1][nf] = __builtin_amdgcn_mfma_f32_16x16x32_bf16(W[1].frag[s], vf, o[1][nf], 0, 0, 0);
        }
        o_l[0] = __builtin_amdgcn_mfma_f32_16x16x32_bf16(W[0].frag[s], onesf, o_l[0], 0, 0, 0);
        o_l[1] = __builtin_amdgcn_mfma_f32_16x16x32_bf16(W[1].frag[s], onesf, o_l[1], 0, 0, 0);
      }
      __builtin_amdgcn_s_setprio(0);
    }

    mbc[0][0] = mbn[0][0]; mbc[0][1] = mbn[0][1];
    mbc[1][0] = mbn[1][0]; mbc[1][1] = mbn[1][1];
  }

  #pragma unroll
  for (int qg = 0; qg < 2; ++qg) {
    float lf[4];
    #pragma unroll
    for (int r = 0; r < 4; ++r) lf[r] = 1.0f / o_l[qg][r];
    #pragma unroll
    for (int nf = 0; nf < 4; ++nf)
      #pragma unroll
      for (int r = 0; r < 4; ++r) {
        const int q = qbase + qg * 16 + lg * 4 + r;
        ctx[((size_t)b * S_LEN + q) * DIM + h * DK + nf * 16 + l15] = (bf16)(o[qg][nf][r] * lf[r]);
      }
  }
}

// ---------------------------------------------------------------------------
extern "C" void kernel_launch(void* const* d_in, const int* in_sizes, int n_in,
                              void* d_out, int out_size, void* d_ws, size_t ws_size,
                              hipStream_t stream)
{
  const float* q    = (const float*)d_in[0];
  const float* k    = (const float*)d_in[1];
  const float* v    = (const float*)d_in[2];
  const int*   mask = (const int*)  d_in[3];
  const float* Wq   = (const float*)d_in[4];
  const float* bq   = (const float*)d_in[5];
  const float* Wk   = (const float*)d_in[6];
  const float* bk   = (const float*)d_in[7];
  const float* Wv   = (const float*)d_in[8];
  const float* bv   = (const float*)d_in[9];
  const float* Wo   = (const float*)d_in[10];
  const float* bo   = (const float*)d_in[11];
  float* out = (float*)d_out;

  const size_t NE = (size_t)BATCH * S_LEN * DIM;  // 8.39M elements
  const size_t NW = (size_t)DIM * DIM;            // 1.05M elements
  bf16* qB  = (bf16*)d_ws;                        // bf16 copies of inputs
  bf16* kB  = qB + NE;
  bf16* vB  = kB + NE;
  bf16* Qb  = vB + NE;                            // projected Q,K,V
  bf16* Kb  = Qb + NE;
  bf16* Vt  = Kb + NE;
  bf16* WqB = Vt + NE;                            // bf16 weights
  bf16* WkB = WqB + NW;
  bf16* WvB = WkB + NW;
  bf16* WoB = WvB + NW;
  u64*  bits = (u64*)(WoB + NW);                  // 2 MB
  bf16* ctx = qB;                                 // reuse: qB dead after QKV GEMMs

  conv_pack<<<dim3(4096, 4), 256, 0, stream>>>(q, k, v, Wq, Wk, Wv, Wo,
                                               qB, kB, vB, WqB, WkB, WvB, WoB);

  gemm_qkv<<<4864, 256, 0, stream>>>(qB, kB, vB, WqB, WkB, WvB,
                                     bq, bk, bv, Qb, Kb, Vt, mask, bits);

  attn_fwd<<<512, 512, 0, stream>>>(Qb, Kb, Vt, bits, ctx);

  gemm_out<<<256, 256, 0, stream>>>(ctx, WoB, bo, out);
}

// Round 21
// 219.970 us; speedup vs baseline: 1.1755x; 1.1755x over previous
//
#include <hip/hip_runtime.h>
#include <math.h>

#define S_LEN 2048
#define DIM   1024
#define HEADS 16
#define DK    64
#define BATCH 4

typedef __bf16 bf16;
typedef bf16  bf16x8 __attribute__((ext_vector_type(8)));
typedef bf16  bf16x4 __attribute__((ext_vector_type(4)));
typedef float f32x4  __attribute__((ext_vector_type(4)));
typedef unsigned long long u64;

#define QSCALE (0.125f * 1.44269504088896f)   // 1/sqrt(dk) * log2(e)

__device__ __forceinline__ void gload16(const void* g, void* l) {
  __builtin_amdgcn_global_load_lds((const __attribute__((address_space(1))) void*)g,
                                   (__attribute__((address_space(3))) void*)l, 16, 0, 0);
}
__device__ __forceinline__ float exp2fast(float x) {
  float r; asm("v_exp_f32 %0, %1" : "=v"(r) : "v"(x)); return r;
}
__device__ __forceinline__ unsigned cvt_pk_bf16(float a, float b) {
  unsigned r; asm("v_cvt_pk_bf16_f32 %0, %1, %2" : "=v"(r) : "v"(a), "v"(b)); return r;
}

// ---------------------------------------------------------------------------
// Combined BW-bound pass: f32->bf16 conversion of all 7 tensors + mask
// bitpack (y==4; tiny-LDS streaming blocks -- round-20 lesson: pack blocks
// must NOT live inside a high-LDS kernel, they serialize against residency).
// ---------------------------------------------------------------------------
__global__ __launch_bounds__(256)
void conv_pack(const float* __restrict__ q, const float* __restrict__ k,
               const float* __restrict__ v,
               const float* __restrict__ Wq, const float* __restrict__ Wk,
               const float* __restrict__ Wv, const float* __restrict__ Wo,
               bf16* __restrict__ qB, bf16* __restrict__ kB, bf16* __restrict__ vB,
               bf16* __restrict__ WqB, bf16* __restrict__ WkB,
               bf16* __restrict__ WvB, bf16* __restrict__ WoB,
               const int* __restrict__ mask, u64* __restrict__ bits)
{
  const int y = blockIdx.y;
  if (y == 4) {
    const int lane = threadIdx.x & 63;
    const size_t w0 = (size_t)blockIdx.x * 64 + (threadIdx.x >> 6);
    #pragma unroll
    for (int it = 0; it < 16; ++it) {
      const size_t w = w0 + it * 4;
      const u64 bb = __ballot(mask[w * 64 + lane] != 0);
      if (lane == 0) bits[w] = bb;
    }
    return;
  }
  const float* in;
  bf16* out;
  size_t idx;
  if (y < 3) {
    in  = (y == 0) ? q  : (y == 1) ? k  : v;
    out = (y == 0) ? qB : (y == 1) ? kB : vB;
    idx = ((size_t)blockIdx.x * 256 + threadIdx.x) * 8;
  } else {
    if (blockIdx.x >= 2048) return;
    const int wsel = blockIdx.x >> 9, inner = blockIdx.x & 511;
    in  = (wsel == 0) ? Wq  : (wsel == 1) ? Wk  : (wsel == 2) ? Wv  : Wo;
    out = (wsel == 0) ? WqB : (wsel == 1) ? WkB : (wsel == 2) ? WvB : WoB;
    idx = ((size_t)inner * 256 + threadIdx.x) * 8;
  }
  float4 a = *reinterpret_cast<const float4*>(&in[idx]);
  float4 b = *reinterpret_cast<const float4*>(&in[idx + 4]);
  bf16x8 r;
  r[0] = (bf16)a.x; r[1] = (bf16)a.y; r[2] = (bf16)a.z; r[3] = (bf16)a.w;
  r[4] = (bf16)b.x; r[5] = (bf16)b.y; r[6] = (bf16)b.z; r[7] = (bf16)b.w;
  *reinterpret_cast<bf16x8*>(&out[idx]) = r;
}

// ---------------------------------------------------------------------------
// GEMM v2 plumbing (round-19 structure): BM=256, BN=128, BK=32, 4x8 frag,
// 3 LDS buffers, depth-2 counted vmcnt.
// ---------------------------------------------------------------------------
#define G2_SETUP()                                                             \
  const int lane = tid & 63;                                                   \
  const int l15  = lane & 15, lg = lane >> 4;                                  \
  const int w    = tid >> 6;                                                   \
  const char* srcA0; const char* srcA1; const char* srcA2; const char* srcA3;  \
  const char* srcB0; const char* srcB1;                                        \
  char* dA0; char* dA1; char* dA2; char* dA3; char* dB0; char* dB1;            \
  {                                                                            \
    char* base = (char*)&AB[0];                                                \
    _Pragma("unroll")                                                          \
    for (int j = 0; j < 4; ++j) {                                              \
      const int c = j * 256 + tid;                                             \
      const int r = c >> 2;                                                    \
      const int cG = ((c & 3) << 4) ^ (((r >> 1) & 3) << 4);                   \
      const char* s = (const char*)A + (size_t)(m0 + r) * 2048 + cG;           \
      char* d = base + c * 16;                                                 \
      if (j == 0) { srcA0 = s; dA0 = d; } else if (j == 1) { srcA1 = s; dA1 = d; } \
      else if (j == 2) { srcA2 = s; dA2 = d; } else { srcA3 = s; dA3 = d; }    \
    }                                                                          \
    _Pragma("unroll")                                                          \
    for (int j = 0; j < 2; ++j) {                                              \
      const int c = j * 256 + tid;                                             \
      const int r = c >> 2;                                                    \
      const int cG = ((c & 3) << 4) ^ (((r >> 1) & 3) << 4);                   \
      const char* s = (const char*)W + (size_t)(n0 + r) * 2048 + cG;           \
      char* d = base + 16384 + c * 16;                                         \
      if (j == 0) { srcB0 = s; dB0 = d; } else { srcB1 = s; dB1 = d; }         \
    }                                                                          \
  }

#define G2_STAGE(SB) do {                                                      \
    gload16(srcA0, dA0 + (SB)); gload16(srcA1, dA1 + (SB));                    \
    gload16(srcA2, dA2 + (SB)); gload16(srcA3, dA3 + (SB));                    \
    gload16(srcB0, dB0 + (SB)); gload16(srcB1, dB1 + (SB));                    \
    srcA0 += 64; srcA1 += 64; srcA2 += 64; srcA3 += 64;                        \
    srcB0 += 64; srcB1 += 64;                                                  \
  } while (0)

#define G2_MAINLOOP()                                                          \
  G2_STAGE(0);                                                                 \
  G2_STAGE(24576);                                                             \
  const unsigned aswz = ((l15 >> 1) & 3) << 4;                                 \
  const unsigned aoff = (unsigned)(w * 64 + l15) * 64 + ((lg * 16) ^ aswz);    \
  const unsigned boff = 16384u + (unsigned)l15 * 64 + ((lg * 16) ^ aswz);      \
  const char* ABB = (const char*)&AB[0];                                       \
  unsigned tb = 0, sb = 2u * 24576;                                            \
  f32x4 acc[4][8] = {};                                                        \
  for (int t = 0; t < 32; ++t) {                                               \
    if (t < 30) {                                                              \
      G2_STAGE(sb);                                                            \
      asm volatile("s_waitcnt vmcnt(12)" ::: "memory");                        \
    } else if (t == 30) {                                                      \
      asm volatile("s_waitcnt vmcnt(6)" ::: "memory");                         \
    } else {                                                                   \
      asm volatile("s_waitcnt vmcnt(0)" ::: "memory");                         \
    }                                                                          \
    __builtin_amdgcn_s_barrier();                                              \
    asm volatile("" ::: "memory");                                             \
    bf16x8 af[4], bfr[8];                                                      \
    _Pragma("unroll")                                                          \
    for (int i = 0; i < 4; ++i)                                                \
      af[i]  = *reinterpret_cast<const bf16x8*>(ABB + tb + aoff + i * 1024);   \
    _Pragma("unroll")                                                          \
    for (int i = 0; i < 8; ++i)                                                \
      bfr[i] = *reinterpret_cast<const bf16x8*>(ABB + tb + boff + i * 1024);   \
    __builtin_amdgcn_s_setprio(1);                                             \
    _Pragma("unroll")                                                          \
    for (int mi = 0; mi < 4; ++mi)                                             \
      _Pragma("unroll")                                                        \
      for (int ni = 0; ni < 8; ++ni)                                           \
        acc[mi][ni] = __builtin_amdgcn_mfma_f32_16x16x32_bf16(af[mi], bfr[ni], acc[mi][ni], 0, 0, 0); \
    __builtin_amdgcn_s_setprio(0);                                             \
    asm volatile("" ::: "memory");                                             \
    __builtin_amdgcn_s_barrier();                                              \
    asm volatile("" ::: "memory");                                             \
    tb = (tb == 2u * 24576) ? 0u : tb + 24576;                                 \
    sb = (sb == 2u * 24576) ? 0u : sb + 24576;                                 \
  }

// Merged QKV: grid 768 (clean, no pack tail).
__global__ __launch_bounds__(256, 2)
void gemm_qkv(const bf16* __restrict__ qB, const bf16* __restrict__ kB,
              const bf16* __restrict__ vB,
              const bf16* __restrict__ WqB, const bf16* __restrict__ WkB,
              const bf16* __restrict__ WvB,
              const float* __restrict__ bq, const float* __restrict__ bk,
              const float* __restrict__ bv,
              bf16* __restrict__ Qb, bf16* __restrict__ Kb,
              bf16* __restrict__ Vt)
{
  __shared__ __align__(16) char AB[3 * 24576];   // 72 KB
  const int tid = threadIdx.x;
  const int which = blockIdx.x >> 8;
  const int inner = blockIdx.x & 255;
  const bf16* A     = (which == 0) ? qB  : (which == 1) ? kB  : vB;
  const bf16* W     = (which == 0) ? WqB : (which == 1) ? WkB : WvB;
  const float* bias = (which == 0) ? bq  : (which == 1) ? bk  : bv;

  const int L  = (inner & 7) * 32 + (inner >> 3);   // XCD-chunked
  const int m0 = (L >> 3) * 256, n0 = (L & 7) * 128;

  G2_SETUP();
  G2_MAINLOOP();

  #pragma unroll
  for (int ni = 0; ni < 8; ++ni) {
    const int col = n0 + ni * 16 + l15;
    const float bi = bias[col];
    #pragma unroll
    for (int mi = 0; mi < 4; ++mi) {
      const int row0 = m0 + w * 64 + mi * 16 + lg * 4;
      if (which == 0) {
        #pragma unroll
        for (int r = 0; r < 4; ++r)
          Qb[(size_t)(row0 + r) * DIM + col] = (bf16)((acc[mi][ni][r] + bi) * QSCALE);
      } else if (which == 1) {
        #pragma unroll
        for (int r = 0; r < 4; ++r)
          Kb[(size_t)(row0 + r) * DIM + col] = (bf16)(acc[mi][ni][r] + bi);
      } else {
        bf16x4 vv;
        #pragma unroll
        for (int r = 0; r < 4; ++r) vv[r] = (bf16)(acc[mi][ni][r] + bi);
        const int seq = row0 & (S_LEN - 1);
        const int t6  = seq & 63;
        const int p0  = (seq & ~63) + ((t6 >> 5) << 5) + (((t6 >> 2) & 3) << 3)
                      + (((t6 >> 4) & 1) << 2);
        *reinterpret_cast<bf16x4*>(
            &Vt[((size_t)(row0 >> 11) * DIM + col) * S_LEN + p0]) = vv;
      }
    }
  }
}

// O-projection (unchanged round-19 structure).
__global__ __launch_bounds__(256, 2)
void gemm_out(const bf16* __restrict__ A, const bf16* __restrict__ W,
              const float* __restrict__ bias, float* __restrict__ out)
{
  __shared__ __align__(16) char AB[3 * 24576];
  const int tid = threadIdx.x;
  const int L  = (blockIdx.x & 7) * 32 + (blockIdx.x >> 3);
  const int m0 = (L >> 3) * 256, n0 = (L & 7) * 128;

  G2_SETUP();
  G2_MAINLOOP();

  #pragma unroll
  for (int ni = 0; ni < 8; ++ni) {
    const int col = n0 + ni * 16 + l15;
    const float bi = bias[col];
    #pragma unroll
    for (int mi = 0; mi < 4; ++mi) {
      const int row0 = m0 + w * 64 + mi * 16 + lg * 4;
      #pragma unroll
      for (int r = 0; r < 4; ++r)
        out[(size_t)(row0 + r) * DIM + col] = acc[mi][ni][r] + bi;
    }
  }
}

// ---------------------------------------------------------------------------
// Flash attention (round-20, kept -- measured ~75 us): KVBLK=128 staging
// (K 2x16KB + V 2x16KB LDS), two 64-kv compute halves per staged tile ->
// half the barrier/drain events; V 256B rows swizzled (l15&7)<<5.
// ---------------------------------------------------------------------------
__global__ __launch_bounds__(512, 2)
void attn_fwd(const bf16* __restrict__ Qb, const bf16* __restrict__ Kb,
              const bf16* __restrict__ Vt, const u64* __restrict__ mbits,
              bf16* __restrict__ ctx)
{
  __shared__ __align__(16) bf16 Kbuf[2][128][64];   // 2 x 16 KB, rows 128 B
  __shared__ __align__(16) bf16 Vbuf[2][64][128];   // 2 x 16 KB, rows 256 B
  __shared__ u64 lutm[16];

  const int tid  = threadIdx.x;
  const int lane = tid & 63;
  const int l15  = lane & 15, lg = lane >> 4;
  const int L  = (blockIdx.x & 7) * 64 + (blockIdx.x >> 3);
  const int qi = L & 7;
  const int hb = L >> 3;
  const int h  = hb & 15, b = hb >> 4;
  const int w  = tid >> 6;
  const int qbase = qi * 256 + w * 32;

  if (tid < 16) {
    lutm[tid] = ((tid & 1) ? 0xFFFFull : 0) | ((tid & 2) ? 0xFFFF0000ull : 0)
              | ((tid & 4) ? 0xFFFF00000000ull : 0)
              | ((tid & 8) ? 0xFFFF000000000000ull : 0);
  }

  const int krr = tid >> 3;
  const int kcG = ((tid & 7) << 4) ^ ((krr & 7) << 4);
  const char* gk0 = (const char*)Kb + ((size_t)(b * S_LEN + krr) * DIM + h * DK) * 2 + kcG;
  const char* gk1 = (const char*)Kb + ((size_t)(b * S_LEN + krr + 64) * DIM + h * DK) * 2 + kcG;
  const int vrr = tid >> 4;
  const unsigned vcG = (unsigned)(((tid & 15) << 4) ^ ((vrr & 7) << 5));
  const char* gv0 = (const char*)Vt + ((size_t)b * DIM + h * DK + vrr) * (S_LEN * 2) + vcG;
  const char* gv1 = (const char*)Vt + ((size_t)b * DIM + h * DK + vrr + 32) * (S_LEN * 2) + vcG;
  char* lK0 = (char*)&Kbuf[0][0][0] + tid * 16;
  char* lV0 = (char*)&Vbuf[0][0][0] + tid * 16;

  const unsigned xo  = (l15 & 7) << 4;
  const unsigned ko0 = l15 * 128 + ((lg * 16) ^ xo);
  const unsigned ko1 = l15 * 128 + (((64 + lg * 16)) ^ xo);
  const unsigned vo0 = l15 * 256 + ((lg * 16) ^ ((l15 & 3) << 5));
  const unsigned vo1 = l15 * 256 + (((64 + lg * 16)) ^ ((l15 & 3) << 5));
  const unsigned vhx = (l15 & 4) << 5;
  const char* KB = (const char*)&Kbuf[0][0][0];
  const char* VB = (const char*)&Vbuf[0][0][0];

  bf16x8 qf[2][2];
  #pragma unroll
  for (int qg = 0; qg < 2; ++qg) {
    const size_t qrow = (size_t)b * S_LEN + qbase + qg * 16 + l15;
    #pragma unroll
    for (int s = 0; s < 2; ++s)
      qf[qg][s] = *reinterpret_cast<const bf16x8*>(&Qb[qrow * DIM + h * DK + s * 32 + lg * 8]);
  }

  bf16x8 onesf;
  #pragma unroll
  for (int j = 0; j < 8; ++j) onesf[j] = (bf16)1.0f;

  union pqu { unsigned u[8]; bf16x8 frag[2]; };

  f32x4 o[2][4] = {};
  f32x4 o_l[2] = {};
  const u64* mp0 = mbits + ((size_t)b * S_LEN + qbase + l15) * (S_LEN / 64);
  const u64* mp1 = mp0 + (size_t)16 * (S_LEN / 64);

  gload16(gk0, lK0); gload16(gk1, lK0 + 8192);
  gload16(gv0, lV0); gload16(gv1, lV0 + 8192);
  gk0 += 128 * DIM * 2; gk1 += 128 * DIM * 2;
  gv0 += 256;           gv1 += 256;
  u64 mbc[2][2] = { { mp0[0], mp0[1] }, { mp1[0], mp1[1] } };
  mp0 += 2; mp1 += 2;

  const int NT = S_LEN / 128;   // 16
  for (int t = 0; t < NT; ++t) {
    asm volatile("s_waitcnt vmcnt(0)" ::: "memory");
    __syncthreads();

    u64 mbn[2][2] = {{0,0},{0,0}};
    if (t + 1 < NT) {
      mbn[0][0] = mp0[0]; mbn[0][1] = mp0[1];
      mbn[1][0] = mp1[0]; mbn[1][1] = mp1[1];
      mp0 += 2; mp1 += 2;
      const unsigned nb = ((t + 1) & 1) << 14;
      gload16(gk0, lK0 + nb); gload16(gk1, lK0 + nb + 8192);
      gload16(gv0, lV0 + nb); gload16(gv1, lV0 + nb + 8192);
      gk0 += 128 * DIM * 2; gk1 += 128 * DIM * 2;
      gv0 += 256;           gv1 += 256;
    }

    const unsigned tb = (t & 1) << 14;

    #pragma unroll
    for (int half = 0; half < 2; ++half) {
      const unsigned kbase = tb + half * 8192;
      const unsigned vbase = tb + (((unsigned)(half << 7)) ^ vhx);

      f32x4 sc[2][4] = {};
      __builtin_amdgcn_s_setprio(1);
      #pragma unroll
      for (int s = 0; s < 2; ++s) {
        const char* kp = KB + kbase + (s ? ko1 : ko0);
        #pragma unroll
        for (int nf = 0; nf < 4; ++nf) {
          bf16x8 kf = *reinterpret_cast<const bf16x8*>(kp + nf * 2048);
          sc[0][nf] = __builtin_amdgcn_mfma_f32_16x16x32_bf16(kf, qf[0][s], sc[0][nf], 0, 0, 0);
          sc[1][nf] = __builtin_amdgcn_mfma_f32_16x16x32_bf16(kf, qf[1][s], sc[1][nf], 0, 0, 0);
        }
      }
      __builtin_amdgcn_s_setprio(0);

      pqu W[2];
      #pragma unroll
      for (int qg = 0; qg < 2; ++qg) {
        const u64 sh = mbc[qg][half] >> (lg * 4);
        #pragma unroll
        for (int nf = 0; nf < 4; ++nf) {
          const unsigned idx = ((unsigned)(sh >> (nf * 16))) & 15u;
          const u64 mk = lutm[idx];
          float e0 = exp2fast(sc[qg][nf][0]);
          float e1 = exp2fast(sc[qg][nf][1]);
          float e2 = exp2fast(sc[qg][nf][2]);
          float e3 = exp2fast(sc[qg][nf][3]);
          W[qg].u[nf * 2 + 0] = cvt_pk_bf16(e0, e1) & (unsigned)mk;
          W[qg].u[nf * 2 + 1] = cvt_pk_bf16(e2, e3) & (unsigned)(mk >> 32);
        }
      }

      __builtin_amdgcn_s_setprio(1);
      #pragma unroll
      for (int s = 0; s < 2; ++s) {
        const char* vp = VB + vbase + (s ? vo1 : vo0);
        #pragma unroll
        for (int nf = 0; nf < 4; ++nf) {
          bf16x8 vf = *reinterpret_cast<const bf16x8*>(vp + nf * 4096);
          o[0][nf] = __builtin_amdgcn_mfma_f32_16x16x32_bf16(W[0].frag[s], vf, o[0][nf], 0, 0, 0);
          o[1][nf] = __builtin_amdgcn_mfma_f32_16x16x32_bf16(W[1].frag[s], vf, o[1][nf], 0, 0, 0);
        }
        o_l[0] = __builtin_amdgcn_mfma_f32_16x16x32_bf16(W[0].frag[s], onesf, o_l[0], 0, 0, 0);
        o_l[1] = __builtin_amdgcn_mfma_f32_16x16x32_bf16(W[1].frag[s], onesf, o_l[1], 0, 0, 0);
      }
      __builtin_amdgcn_s_setprio(0);
    }

    mbc[0][0] = mbn[0][0]; mbc[0][1] = mbn[0][1];
    mbc[1][0] = mbn[1][0]; mbc[1][1] = mbn[1][1];
  }

  #pragma unroll
  for (int qg = 0; qg < 2; ++qg) {
    float lf[4];
    #pragma unroll
    for (int r = 0; r < 4; ++r) lf[r] = 1.0f / o_l[qg][r];
    #pragma unroll
    for (int nf = 0; nf < 4; ++nf)
      #pragma unroll
      for (int r = 0; r < 4; ++r) {
        const int q = qbase + qg * 16 + lg * 4 + r;
        ctx[((size_t)b * S_LEN + q) * DIM + h * DK + nf * 16 + l15] = (bf16)(o[qg][nf][r] * lf[r]);
      }
  }
}

// ---------------------------------------------------------------------------
extern "C" void kernel_launch(void* const* d_in, const int* in_sizes, int n_in,
                              void* d_out, int out_size, void* d_ws, size_t ws_size,
                              hipStream_t stream)
{
  const float* q    = (const float*)d_in[0];
  const float* k    = (const float*)d_in[1];
  const float* v    = (const float*)d_in[2];
  const int*   mask = (const int*)  d_in[3];
  const float* Wq   = (const float*)d_in[4];
  const float* bq   = (const float*)d_in[5];
  const float* Wk   = (const float*)d_in[6];
  const float* bk   = (const float*)d_in[7];
  const float* Wv   = (const float*)d_in[8];
  const float* bv   = (const float*)d_in[9];
  const float* Wo   = (const float*)d_in[10];
  const float* bo   = (const float*)d_in[11];
  float* out = (float*)d_out;

  const size_t NE = (size_t)BATCH * S_LEN * DIM;  // 8.39M elements
  const size_t NW = (size_t)DIM * DIM;            // 1.05M elements
  bf16* qB  = (bf16*)d_ws;                        // bf16 copies of inputs
  bf16* kB  = qB + NE;
  bf16* vB  = kB + NE;
  bf16* Qb  = vB + NE;                            // projected Q,K,V
  bf16* Kb  = Qb + NE;
  bf16* Vt  = Kb + NE;
  bf16* WqB = Vt + NE;                            // bf16 weights
  bf16* WkB = WqB + NW;
  bf16* WvB = WkB + NW;
  bf16* WoB = WvB + NW;
  u64*  bits = (u64*)(WoB + NW);                  // 2 MB
  bf16* ctx = qB;                                 // reuse: qB dead after QKV GEMMs

  conv_pack<<<dim3(4096, 5), 256, 0, stream>>>(q, k, v, Wq, Wk, Wv, Wo,
                                               qB, kB, vB, WqB, WkB, WvB, WoB,
                                               mask, bits);

  gemm_qkv<<<768, 256, 0, stream>>>(qB, kB, vB, WqB, WkB, WvB,
                                    bq, bk, bv, Qb, Kb, Vt);

  attn_fwd<<<512, 512, 0, stream>>>(Qb, Kb, Vt, bits, ctx);

  gemm_out<<<256, 256, 0, stream>>>(ctx, WoB, bo, out);
}